// Round 14
// baseline (515.232 us; speedup 1.0000x reference)
//
#include <hip/hip_runtime.h>
#include <stdint.h>
#include <math.h>

typedef unsigned long long u64;
typedef unsigned int u32;
typedef unsigned short u16;

// ---- problem constants ----
#define C_P 32
#define C_S 16
#define C_D 64
#define C_N 2048

// ---- ws layout (offsets in doubles) ----
#define R_OFF      0        // float[4096]
#define CTAB_OFF   4160     // double[64]
#define KEYS_OFF   4224     // u32[4]
#define PROBS_OFF  4232     // float[131072]
#define GROW_OFF   135304   // u64[32768] row masks
#define GCOL_OFF   168072   // u64[32768] col masks
#define NS_OFF     200840   // double[32768]; later grow2 u64[2048]
#define W_OFF      233608   // double[512]
#define GF_OFF     234120   // float[262144]
#define KM_OFF     365192   // float[1024]
#define ZN_OFF     365704   // float[262144]
#define NS2_OFF    496776   // double[2048]

// ---- out layout (FLOAT32 elements) ----
#define O_REC   0
#define O_LOGP  4096
#define O_QZ    4128
#define O_QMU   6176
#define O_QLV   8224
#define O_GH    10272
#define O_ZN    141344
#define O_TOTAL 403488

__device__ __forceinline__ void tf2x32(u32 k0, u32 k1, u32 x0, u32 x1,
                                       u32& o0, u32& o1) {
  u32 ks2 = k0 ^ k1 ^ 0x1BD11BDAu;
  x0 += k0; x1 += k1;
#define TFR(r) { x0 += x1; x1 = (x1 << r) | (x1 >> (32 - r)); x1 ^= x0; }
  TFR(13) TFR(15) TFR(26) TFR(6)   x0 += k1;  x1 += ks2 + 1u;
  TFR(17) TFR(29) TFR(16) TFR(24)  x0 += ks2; x1 += k0 + 2u;
  TFR(13) TFR(15) TFR(26) TFR(6)   x0 += k0;  x1 += k1 + 3u;
  TFR(17) TFR(29) TFR(16) TFR(24)  x0 += k1;  x1 += ks2 + 4u;
  TFR(13) TFR(15) TFR(26) TFR(6)   x0 += ks2; x1 += k0 + 5u;
#undef TFR
  o0 = x0; o1 = x1;
}

__device__ __forceinline__ double d_erfinv(double x) {
  double w = -log1p(-x * x);
  double p;
  if (w < 5.0) {
    w -= 2.5;
    p = 2.81022636e-08;
    p = 3.43273939e-07  + p * w;
    p = -3.5233877e-06  + p * w;
    p = -4.39150654e-06 + p * w;
    p = 0.00021858087   + p * w;
    p = -0.00125372503  + p * w;
    p = -0.00417768164  + p * w;
    p = 0.246640727     + p * w;
    p = 1.50140941      + p * w;
  } else {
    w = sqrt(w) - 3.0;
    p = -0.000200214257;
    p = 0.000100950558  + p * w;
    p = 0.00134934322   + p * w;
    p = -0.00367342844  + p * w;
    p = 0.00573950773   + p * w;
    p = -0.0076224613   + p * w;
    p = 0.00943887047   + p * w;
    p = 1.00167406      + p * w;
    p = 2.83297682      + p * w;
  }
  return p * x;
}

// R (with fused setup on block 0): one pass Sx/Sxx, combine analytically.
__global__ void k_R(const float* x, double* ws, const int* seedp) {
  __shared__ double pS[8][64], pX[8][64];
  __shared__ double xbar[64];
  int j = blockIdx.x, t = threadIdx.x;   // 512 threads
  int i = t & 63, c = t >> 6;
  if (j == 0) {                          // fused k_setup
    if (t < 64) {
      double l = (double)t;
      ws[CTAB_OFF + t] = -0.5 * log(2049.0)
                       + lgamma(0.5 * (2051.0 + l))
                       - lgamma(0.5 * (3.0 + l))
                       - 1024.0 * log(3.14159265358979323846)
                       + 0.5 * (2.0 * l + 3.0) * log(0.5);
    }
    if (t == 0) {
      u32 kk0 = 0u, kk1 = (u32)seedp[0];
      u32 a0, a1, s0, s1, r0, r1, d0, d1;
      tf2x32(kk0, kk1, 0u, 0u, a0, a1);
      tf2x32(kk0, kk1, 0u, 1u, s0, s1);   // sk (bernoulli)
      tf2x32(a0, a1, 0u, 0u, d0, d1); (void)d0; (void)d1;
      tf2x32(a0, a1, 0u, 1u, r0, r1);     // rk (normal eps)
      u32* keys = (u32*)(ws + KEYS_OFF);
      keys[0] = s0; keys[1] = s1; keys[2] = r0; keys[3] = r1;
    }
  }
  double sx = 0.0, sxx = 0.0;
  for (int n = c * 256; n < (c + 1) * 256; n++) {
    double xi = (double)x[n * 64 + i];
    double xj = (double)x[n * 64 + j];
    sx += xi; sxx += xi * xj;
  }
  pS[c][i] = sx; pX[c][i] = sxx;
  __syncthreads();
  if (t < 64) {
    double S = 0.0, X = 0.0;
    for (int cc = 0; cc < 8; cc++) { S += pS[cc][i]; X += pX[cc][i]; }
    xbar[i] = S / 2048.0;
    pX[0][i] = X;
  }
  __syncthreads();
  if (t < 64) {
    double xbi = xbar[i], xbj = xbar[j];
    double s = pX[0][i] - 2048.0 * xbi * xbj + (2048.0 / 2049.0) * xbi * xbj;
    if (i == j) s += 0.5;
    ((float*)(ws + R_OFF))[i * 64 + j] = (float)s;
  }
}

// probs[p,i,j] = sigmoid(alpha * u_i . v_j) * (i!=j), stored f32
__global__ __launch_bounds__(64) void k_probs(const float* z, double* ws) {
  float* probs = (float*)(ws + PROBS_OFF);
  int b = blockIdx.x; int p = b >> 6, i = b & 63;
  int j = threadIdx.x;
  __shared__ float V[64 * 65];
  __shared__ float us[64];
  int k = j;
  us[k] = z[((p * 64 + i) * 64 + k) * 2 + 0];
  for (int jj = 0; jj < 64; jj++)
    V[jj * 65 + k] = z[((p * 64 + jj) * 64 + k) * 2 + 1];
  __syncthreads();
  float s = 0.f;
  for (int kk = 0; kk < 64; kk++)
    s += us[kk] * V[j * 65 + kk];
  float pr = (i == j) ? 0.f : 1.f / (1.f + expf(-0.2f * s));
  probs[(p * 64 + i) * 64 + j] = pr;
}

__global__ void k_sample(double* ws) {
  const float* probs = (const float*)(ws + PROBS_OFF);
  const u32* keys = (const u32*)(ws + KEYS_OFF);
  u64* grow = (u64*)(ws + GROW_OFF);
  u64* gcol = (u64*)(ws + GCOL_OFF);
  int ps = blockIdx.x;
  int p = ps >> 4;
  int j = threadIdx.x;
  u32 k0 = keys[0], k1 = keys[1];
  u64 colmask = 0;
  for (int i = 0; i < 64; i++) {
    u32 lin = (u32)(ps * 4096 + i * 64 + j);
    u32 o0, o1; tf2x32(k0, k1, 0u, lin, o0, o1);
    u32 bits = o0 ^ o1;
    float f = __uint_as_float((bits >> 9) | 0x3f800000u) - 1.0f;
    bool bit = (f < probs[(p * 64 + i) * 64 + j]);
    u64 rm = __ballot(bit);
    if (j == 0) grow[ps * 64 + i] = rm;
    if (bit) colmask |= (1ull << i);
  }
  gcol[ps * 64 + j] = colmask;
}

__device__ __forceinline__ float rdlane(float x, int l) {
  return __uint_as_float(__builtin_amdgcn_readlane(__float_as_uint(x), (u32)l));
}

// Merged f32 LDL Cholesky: block-uniform branch on m.
//  m<=40 (~98%): register path v[40] (44 VGPR, full unroll, readlane).
//  m>40  (~2%):  in-place LDS LDL on triangular T (dynamic bounds, ~20 VGPR)
//                — hidden under the light blocks in the same dispatch.
// Keeps VGPR ~44 (r12's merged v[64] path cost VGPR 80 / -25us; r13's split
// serialized the heavy tasks / -32us. This gets both properties in 1 launch.)
template<bool TRANSPOSE>
__global__ __launch_bounds__(64) void k_chol(const float* Rf, const double* ctab,
                                             const u64* masks, double* nodescore) {
  __shared__ float T[2080];
  __shared__ int idx[64];
  int task = blockIdx.x;
  int j = task & 63;
  int lane = threadIdx.x;
  u64 mask;
  if (TRANSPOSE) {
    int p = task >> 6;
    u64 rm = masks[p * 64 + lane];       // row mask of row `lane`
    mask = __ballot((rm >> j) & 1ull);   // column j mask
  } else {
    mask = masks[task];
  }
  int P = (int)__popcll(mask);
  int m = P + 1;
  u64 below = mask & ((1ull << lane) - 1ull);
  if ((mask >> lane) & 1ull) idx[(int)__popcll(below)] = lane;
  if (lane == 0) idx[P] = j;
  __syncthreads();
  int trLane = (lane * (lane + 1)) >> 1;
  if (lane < m) {
    int cidx = idx[lane];
    int tr = 0;
    for (int r = 0; r < m; r++) {
      if (lane <= r) T[tr + lane] = Rf[idx[r] * 64 + cidx];
      tr += r + 1;
    }
  }
  __syncthreads();
  float mypiv = 1.0f, lastd = 1.0f;
  if (m <= 40) {
    float v[40];
#pragma unroll
    for (int c = 0; c < 40; c++)
      v[c] = T[trLane + c];              // in-bounds garbage for c>lane
#pragma unroll
    for (int k = 0; k < 40; k++) {
      if (k < m) {                       // uniform guard (keeps full unroll)
        float dk = rdlane(v[k], k);
        if (lane == k) mypiv = dk;
        lastd = dk;
        float ns = -v[k] * __builtin_amdgcn_rcpf(dk);
#pragma unroll
        for (int b = k + 1; b < 40; b++)
          v[b] += ns * rdlane(v[k], b);  // garbage slots harmless
      }
    }
  } else {
    // rare heavy path: LDS in-place, dynamic bounds, register-light
    for (int k = 0; k < m; k++) {
      float dk = T[((k * (k + 1)) >> 1) + k];        // broadcast
      if (lane == k) mypiv = dk;
      lastd = dk;
      float sk = T[trLane + k] * __builtin_amdgcn_rcpf(dk);
      for (int b = k + 1; b < m; b++) {
        float abk = T[((b * (b + 1)) >> 1) + k];     // broadcast (col k)
        if (lane >= b && lane < m) T[trLane + b] -= sk * abk;
      }
      __syncthreads();
    }
  }
  double vv = (lane < m) ? log((double)mypiv) : 0.0;
  for (int off = 32; off > 0; off >>= 1) vv += __shfl_down(vv, off, 64);
  if (lane == 0) {
    double logB = vv;
    double logA = logB - log((double)lastd);
    double l = (double)P;
    nodescore[task] = ctab[P]
                    + 0.5 * (2050.0 + l) * logA
                    - 0.5 * (2051.0 + l) * logB;
  }
}

__global__ void k_logpw(const double* ns, double* w) {
  int p = blockIdx.x, t = threadIdx.x;
  __shared__ double part[64];
  int s = t & 15, c = t >> 4;            // 4 chunks x 16 samples
  double acc = 0.0;
  for (int j = c * 16; j < (c + 1) * 16; j++)
    acc += ns[(p * 16 + s) * 64 + j];
  part[t] = acc;
  __syncthreads();
  if (t < 16) part[t] = part[t] + part[t + 16] + part[t + 32] + part[t + 48];
  __syncthreads();
  if (t == 0) {
    double m = part[0];
    for (int s2 = 1; s2 < 16; s2++) m = fmax(m, part[s2]);
    double e[16], sum = 0.0;
    for (int s2 = 0; s2 < 16; s2++) { e[s2] = exp(part[s2] - m); sum += e[s2]; }
    for (int s2 = 0; s2 < 16; s2++) w[p * 16 + s2] = e[s2] / sum;
  }
}

// fused A-construction + grad dot. blocks 0..2047: grad_u; 2048..4095: grad_v.
__global__ void k_grad(double* ws, const float* z) {
  const float* probs = (const float*)(ws + PROBS_OFF);
  const double* w = ws + W_OFF;
  const u64* grow = (const u64*)(ws + GROW_OFF);
  const u64* gcol = (const u64*)(ws + GCOL_OFF);
  float* gf = (float*)(ws + GF_OFF);
  const float LOGIT = -2.6903717578966254f;  // log(4/63)-log1p(-4/63)
  int bb = blockIdx.x;
  int k = threadIdx.x;
  __shared__ float acc[64];
  if (bb < 2048) {
    int p = bb >> 6, i = bb & 63;
    float gb = 0.f, wsum = 0.f;
    for (int s = 0; s < 16; s++) {
      float wv = (float)w[p * 16 + s];
      wsum += wv;
      gb += wv * (float)((grow[(p * 16 + s) * 64 + i] >> k) & 1ull);
    }
    float pr = probs[(p * 64 + i) * 64 + k];   // coalesced
    float od = (i == k) ? 0.f : 1.f;
    acc[k] = (0.2f * (gb - pr * wsum) + 0.2f * pr * (1.f - pr) * LOGIT) * od;
    __syncthreads();
    float s = 0.f;
    for (int j = 0; j < 64; j++)
      s += acc[j] * z[((p * 64 + j) * 64 + k) * 2 + 1];
    s -= 64.f * z[((p * 64 + i) * 64 + k) * 2 + 0];
    gf[p * 8192 + (i * 64 + k) * 2 + 0] = s;
  } else {
    int b = bb - 2048;
    int p = b >> 6, j = b & 63;
    float gb = 0.f, wsum = 0.f;
    for (int s = 0; s < 16; s++) {
      float wv = (float)w[p * 16 + s];
      wsum += wv;
      gb += wv * (float)((gcol[(p * 16 + s) * 64 + j] >> k) & 1ull);
    }
    float pr = probs[(p * 64 + k) * 64 + j];   // one 64-lane gather
    float od = (k == j) ? 0.f : 1.f;
    acc[k] = (0.2f * (gb - pr * wsum) + 0.2f * pr * (1.f - pr) * LOGIT) * od;
    __syncthreads();
    float s = 0.f;
    for (int i = 0; i < 64; i++)
      s += acc[i] * z[((p * 64 + i) * 64 + k) * 2 + 0];
    s -= 64.f * z[((p * 64 + j) * 64 + k) * 2 + 1];
    gf[p * 8192 + (j * 64 + k) * 2 + 1] = s;
  }
}

__global__ void k_kmat(const float* z, double* ws) {
  float* Km = (float*)(ws + KM_OFF);
  int a = blockIdx.x >> 5, b = blockIdx.x & 31;
  int t = threadIdx.x;
  float acc = 0.f;
  for (int d0 = t; d0 < 8192; d0 += 64) {
    float diff = z[a * 8192 + d0] - z[b * 8192 + d0];
    acc += diff * diff;
  }
  for (int off = 32; off > 0; off >>= 1) acc += __shfl_down(acc, off, 64);
  if (t == 0) Km[a * 32 + b] = expf(-acc / 5.0f);
}

__global__ void k_znew(const float* z, double* ws, float* out) {
  const float* Km = (const float*)(ws + KM_OFF);
  const float* gf = (const float*)(ws + GF_OFF);
  float* zn = (float*)(ws + ZN_OFF);
  int gid = blockIdx.x * 64 + threadIdx.x;
  int p = gid >> 13, t = gid & 8191;
  float zp = z[p * 8192 + t];
  float accg = 0.f, accz = 0.f, ks = 0.f;
  for (int b = 0; b < 32; b++) {
    float kv = Km[p * 32 + b];
    accg += kv * gf[b * 8192 + t];
    accz += kv * z[b * 8192 + t];
    ks += kv;
  }
  float rep = -0.4f * (accz - zp * ks);
  float v = zp + 0.005f * ((accg + rep) / 32.f);
  zn[p * 8192 + t] = v;
  out[O_ZN + p * 8192 + t] = v;
}

__global__ __launch_bounds__(64) void k_s2col(double* ws, float* out) {
  const float* zn = (const float*)(ws + ZN_OFF);
  u64* grow2 = (u64*)(ws + NS_OFF);
  int b = blockIdx.x; int p = b >> 6, i = b & 63;
  int j = threadIdx.x;
  __shared__ float V[64 * 65];
  __shared__ float us[64];
  int k = j;
  us[k] = zn[p * 8192 + (i * 64 + k) * 2 + 0];
  for (int jj = 0; jj < 64; jj++)
    V[jj * 65 + k] = zn[p * 8192 + (jj * 64 + k) * 2 + 1];
  __syncthreads();
  float s = 0.f;
  for (int kk = 0; kk < 64; kk++)
    s += us[kk] * V[j * 65 + kk];
  bool bit = (i != j) && (s > 0.0f);
  out[O_GH + (p * 64 + i) * 64 + j] = bit ? 1.0f : 0.0f;
  u64 m = __ballot(bit);
  if (j == 0) grow2[p * 64 + i] = m;    // row masks; k_chol<true> transposes
}

// encoder/decoder MLP; also writes log_p (fused reduction)
__global__ void k_mlp(double* ws, float* out, const double* ns2,
    const float* ew0, const float* eb0, const float* ew1, const float* eb1,
    const float* ew2, const float* eb2,
    const float* mw0, const float* mb0, const float* mw1, const float* mb1,
    const float* lw0, const float* lb0, const float* lw1, const float* lb1,
    const float* dw0, const float* db0, const float* dw1, const float* db1,
    const float* dw2, const float* db2) {
  int p = blockIdx.x, t = threadIdx.x;
  const u64* grow2 = (const u64*)(ws + NS_OFF);
  const u32* keys = (const u32*)(ws + KEYS_OFF);
  __shared__ float part[64][20];
  __shared__ float h0[20], h1[64], h2[64], hm[64], hl[64];
  __shared__ float qmu[64], qlv[64], qz[64], h3[10], h4[128];
  __shared__ u64 gc[64];
  {
    double vv = ns2[p * 64 + t];
    for (int off = 32; off > 0; off >>= 1) vv += __shfl_down(vv, off, 64);
    if (t == 0) out[O_LOGP + p] = (float)vv;
  }
  // column mask: bit i of gc[t] = (rowmask_i >> t) & 1
  {
    u64 cmask = 0;
    for (int i = 0; i < 64; i++)
      cmask |= ((grow2[p * 64 + i] >> t) & 1ull) << i;
    gc[t] = cmask;
  }
  __syncthreads();
  {
    float acc[20];
#pragma unroll
    for (int o = 0; o < 20; o++) acc[o] = 0.f;
    u64 m = gc[t];
    for (int i = 0; i < 64; i++) {
      float msk = (float)((m >> i) & 1ull);
      const float* wr = ew0 + (i * 64 + t) * 20;
#pragma unroll
      for (int o = 0; o < 20; o++) acc[o] += msk * wr[o];
    }
    for (int o = 0; o < 20; o++) part[t][o] = acc[o];
  }
  __syncthreads();
  if (t < 20) {
    float s = eb0[t];
    for (int q = 0; q < 64; q++) s += part[q][t];
    h0[t] = fmaxf(s, 0.f);
  }
  __syncthreads();
  {
    float s = eb1[t];
    for (int q = 0; q < 20; q++) s += h0[q] * ew1[q * 64 + t];
    h1[t] = fmaxf(s, 0.f);
  }
  __syncthreads();
  {
    float s = eb2[t];
    for (int q = 0; q < 64; q++) s += h1[q] * ew2[q * 64 + t];
    h2[t] = fmaxf(s, 0.f);
  }
  __syncthreads();
  {
    float s = mb0[t];
    for (int q = 0; q < 64; q++) s += h2[q] * mw0[q * 64 + t];
    hm[t] = fmaxf(s, 0.f);
    float s2 = lb0[t];
    for (int q = 0; q < 64; q++) s2 += h2[q] * lw0[q * 64 + t];
    hl[t] = fmaxf(s2, 0.f);
  }
  __syncthreads();
  {
    float s = mb1[t];
    for (int q = 0; q < 64; q++) s += hm[q] * mw1[q * 64 + t];
    qmu[t] = s;
    float s2 = lb1[t];
    for (int q = 0; q < 64; q++) s2 += hl[q] * lw1[q * 64 + t];
    qlv[t] = s2;
  }
  {
    u32 o0, o1;
    tf2x32(keys[2], keys[3], 0u, (u32)(p * 64 + t), o0, o1);
    u32 bits = o0 ^ o1;
    float f = __uint_as_float((bits >> 9) | 0x3f800000u) - 1.0f;
    float LOF = __uint_as_float(0xBF7FFFFFu);
    float uu = fmaxf(LOF, f * 2.0f + LOF);
    float eps = (float)(1.4142135623730951 * d_erfinv((double)uu));
    float qzv = qmu[t] + eps * expf(0.5f * qlv[t]);
    qz[t] = qzv;
    out[O_QZ  + p * 64 + t] = qzv;
    out[O_QMU + p * 64 + t] = qmu[t];
    out[O_QLV + p * 64 + t] = qlv[t];
  }
  __syncthreads();
  if (t < 10) {
    float s = db0[t];
    for (int q = 0; q < 64; q++) s += qz[q] * dw0[q * 10 + t];
    h3[t] = fmaxf(s, 0.f);
  }
  __syncthreads();
  for (int o = t; o < 128; o += 64) {
    float s = db1[o];
    for (int q = 0; q < 10; q++) s += h3[q] * dw1[q * 128 + o];
    h4[o] = fmaxf(s, 0.f);
  }
  __syncthreads();
  for (int o = t; o < 128; o += 64) {
    float s = db2[o];
    for (int q = 0; q < 128; q++) s += h4[q] * dw2[q * 128 + o];
    out[O_REC + p * 128 + o] = s;
  }
}

extern "C" void kernel_launch(void* const* d_in, const int* in_sizes, int n_in,
                              void* d_out, int out_size, void* d_ws, size_t ws_size,
                              hipStream_t stream) {
  (void)in_sizes; (void)n_in; (void)out_size; (void)ws_size;
  const float* z_gt = (const float*)d_in[0];
  const float* z0   = (const float*)d_in[1];
  const float* ew0 = (const float*)d_in[2];  const float* eb0 = (const float*)d_in[3];
  const float* ew1 = (const float*)d_in[4];  const float* eb1 = (const float*)d_in[5];
  const float* ew2 = (const float*)d_in[6];  const float* eb2 = (const float*)d_in[7];
  const float* mw0 = (const float*)d_in[8];  const float* mb0 = (const float*)d_in[9];
  const float* mw1 = (const float*)d_in[10]; const float* mb1 = (const float*)d_in[11];
  const float* lw0 = (const float*)d_in[12]; const float* lb0 = (const float*)d_in[13];
  const float* lw1 = (const float*)d_in[14]; const float* lb1 = (const float*)d_in[15];
  const float* dw0 = (const float*)d_in[16]; const float* db0 = (const float*)d_in[17];
  const float* dw1 = (const float*)d_in[18]; const float* db1 = (const float*)d_in[19];
  const float* dw2 = (const float*)d_in[20]; const float* db2 = (const float*)d_in[21];
  const int* seed = (const int*)d_in[22];
  double* ws = (double*)d_ws;
  float* out = (float*)d_out;
  const float* Rf = (const float*)(ws + R_OFF);

  k_R<<<64, 512, 0, stream>>>(z_gt, ws, seed);
  k_probs<<<C_P * C_D, 64, 0, stream>>>(z0, ws);
  k_sample<<<C_P * C_S, 64, 0, stream>>>(ws);
  k_chol<false><<<C_P * C_S * C_D, 64, 0, stream>>>(Rf, ws + CTAB_OFF,
      (const u64*)(ws + GCOL_OFF), ws + NS_OFF);
  k_logpw<<<C_P, 64, 0, stream>>>(ws + NS_OFF, ws + W_OFF);
  k_grad<<<2 * C_P * C_D, 64, 0, stream>>>(ws, z0);
  k_kmat<<<C_P * C_P, 64, 0, stream>>>(z0, ws);
  k_znew<<<(C_P * 8192) / 64, 64, 0, stream>>>(z0, ws, out);
  k_s2col<<<C_P * C_D, 64, 0, stream>>>(ws, out);
  k_chol<true><<<C_P * C_D, 64, 0, stream>>>(Rf, ws + CTAB_OFF,
      (const u64*)(ws + NS_OFF), ws + NS2_OFF);
  k_mlp<<<C_P, 64, 0, stream>>>(ws, out, ws + NS2_OFF,
      ew0, eb0, ew1, eb1, ew2, eb2,
      mw0, mb0, mw1, mb1, lw0, lb0, lw1, lb1,
      dw0, db0, dw1, db1, dw2, db2);
}

// Round 15
// 401.555 us; speedup vs baseline: 1.2831x; 1.2831x over previous
//
#include <hip/hip_runtime.h>
#include <stdint.h>
#include <math.h>

typedef unsigned long long u64;
typedef unsigned int u32;
typedef unsigned short u16;

// ---- problem constants ----
#define C_P 32
#define C_S 16
#define C_D 64
#define C_N 2048

// ---- ws layout (offsets in doubles) ----
#define R_OFF      0        // float[4096]
#define CTAB_OFF   4160     // double[64]
#define KEYS_OFF   4224     // u32[4]
#define PROBS_OFF  4232     // float[131072]
#define GROW_OFF   135304   // u64[32768] row masks
#define GCOL_OFF   168072   // u64[32768] col masks
#define NS_OFF     200840   // double[32768]; later grow2 u64[2048]
#define W_OFF      233608   // double[512]
#define GF_OFF     234120   // float[262144]
#define KM_OFF     365192   // float[1024]
#define ZN_OFF     365704   // float[262144]
#define NS2_OFF    496776   // double[2048]

// ---- out layout (FLOAT32 elements) ----
#define O_REC   0
#define O_LOGP  4096
#define O_QZ    4128
#define O_QMU   6176
#define O_QLV   8224
#define O_GH    10272
#define O_ZN    141344
#define O_TOTAL 403488

__device__ __forceinline__ void tf2x32(u32 k0, u32 k1, u32 x0, u32 x1,
                                       u32& o0, u32& o1) {
  u32 ks2 = k0 ^ k1 ^ 0x1BD11BDAu;
  x0 += k0; x1 += k1;
#define TFR(r) { x0 += x1; x1 = (x1 << r) | (x1 >> (32 - r)); x1 ^= x0; }
  TFR(13) TFR(15) TFR(26) TFR(6)   x0 += k1;  x1 += ks2 + 1u;
  TFR(17) TFR(29) TFR(16) TFR(24)  x0 += ks2; x1 += k0 + 2u;
  TFR(13) TFR(15) TFR(26) TFR(6)   x0 += k0;  x1 += k1 + 3u;
  TFR(17) TFR(29) TFR(16) TFR(24)  x0 += k1;  x1 += ks2 + 4u;
  TFR(13) TFR(15) TFR(26) TFR(6)   x0 += ks2; x1 += k0 + 5u;
#undef TFR
  o0 = x0; o1 = x1;
}

__device__ __forceinline__ double d_erfinv(double x) {
  double w = -log1p(-x * x);
  double p;
  if (w < 5.0) {
    w -= 2.5;
    p = 2.81022636e-08;
    p = 3.43273939e-07  + p * w;
    p = -3.5233877e-06  + p * w;
    p = -4.39150654e-06 + p * w;
    p = 0.00021858087   + p * w;
    p = -0.00125372503  + p * w;
    p = -0.00417768164  + p * w;
    p = 0.246640727     + p * w;
    p = 1.50140941      + p * w;
  } else {
    w = sqrt(w) - 3.0;
    p = -0.000200214257;
    p = 0.000100950558  + p * w;
    p = 0.00134934322   + p * w;
    p = -0.00367342844  + p * w;
    p = 0.00573950773   + p * w;
    p = -0.0076224613   + p * w;
    p = 0.00943887047   + p * w;
    p = 1.00167406      + p * w;
    p = 2.83297682      + p * w;
  }
  return p * x;
}

// R (with fused setup on block 0): one pass Sx/Sxx, combine analytically.
__global__ void k_R(const float* x, double* ws, const int* seedp) {
  __shared__ double pS[8][64], pX[8][64];
  __shared__ double xbar[64];
  int j = blockIdx.x, t = threadIdx.x;   // 512 threads
  int i = t & 63, c = t >> 6;
  if (j == 0) {                          // fused k_setup
    if (t < 64) {
      double l = (double)t;
      ws[CTAB_OFF + t] = -0.5 * log(2049.0)
                       + lgamma(0.5 * (2051.0 + l))
                       - lgamma(0.5 * (3.0 + l))
                       - 1024.0 * log(3.14159265358979323846)
                       + 0.5 * (2.0 * l + 3.0) * log(0.5);
    }
    if (t == 0) {
      u32 kk0 = 0u, kk1 = (u32)seedp[0];
      u32 a0, a1, s0, s1, r0, r1, d0, d1;
      tf2x32(kk0, kk1, 0u, 0u, a0, a1);
      tf2x32(kk0, kk1, 0u, 1u, s0, s1);   // sk (bernoulli)
      tf2x32(a0, a1, 0u, 0u, d0, d1); (void)d0; (void)d1;
      tf2x32(a0, a1, 0u, 1u, r0, r1);     // rk (normal eps)
      u32* keys = (u32*)(ws + KEYS_OFF);
      keys[0] = s0; keys[1] = s1; keys[2] = r0; keys[3] = r1;
    }
  }
  double sx = 0.0, sxx = 0.0;
  for (int n = c * 256; n < (c + 1) * 256; n++) {
    double xi = (double)x[n * 64 + i];
    double xj = (double)x[n * 64 + j];
    sx += xi; sxx += xi * xj;
  }
  pS[c][i] = sx; pX[c][i] = sxx;
  __syncthreads();
  if (t < 64) {
    double S = 0.0, X = 0.0;
    for (int cc = 0; cc < 8; cc++) { S += pS[cc][i]; X += pX[cc][i]; }
    xbar[i] = S / 2048.0;
    pX[0][i] = X;
  }
  __syncthreads();
  if (t < 64) {
    double xbi = xbar[i], xbj = xbar[j];
    double s = pX[0][i] - 2048.0 * xbi * xbj + (2048.0 / 2049.0) * xbi * xbj;
    if (i == j) s += 0.5;
    ((float*)(ws + R_OFF))[i * 64 + j] = (float)s;
  }
}

// probs[p,i,j] = sigmoid(alpha * u_i . v_j) * (i!=j), stored f32
__global__ __launch_bounds__(64) void k_probs(const float* z, double* ws) {
  float* probs = (float*)(ws + PROBS_OFF);
  int b = blockIdx.x; int p = b >> 6, i = b & 63;
  int j = threadIdx.x;
  __shared__ float V[64 * 65];
  __shared__ float us[64];
  int k = j;
  us[k] = z[((p * 64 + i) * 64 + k) * 2 + 0];
  for (int jj = 0; jj < 64; jj++)
    V[jj * 65 + k] = z[((p * 64 + jj) * 64 + k) * 2 + 1];
  __syncthreads();
  float s = 0.f;
  for (int kk = 0; kk < 64; kk++)
    s += us[kk] * V[j * 65 + kk];
  float pr = (i == j) ? 0.f : 1.f / (1.f + expf(-0.2f * s));
  probs[(p * 64 + i) * 64 + j] = pr;
}

__global__ void k_sample(double* ws) {
  const float* probs = (const float*)(ws + PROBS_OFF);
  const u32* keys = (const u32*)(ws + KEYS_OFF);
  u64* grow = (u64*)(ws + GROW_OFF);
  u64* gcol = (u64*)(ws + GCOL_OFF);
  int ps = blockIdx.x;
  int p = ps >> 4;
  int j = threadIdx.x;
  u32 k0 = keys[0], k1 = keys[1];
  u64 colmask = 0;
  for (int i = 0; i < 64; i++) {
    u32 lin = (u32)(ps * 4096 + i * 64 + j);
    u32 o0, o1; tf2x32(k0, k1, 0u, lin, o0, o1);
    u32 bits = o0 ^ o1;
    float f = __uint_as_float((bits >> 9) | 0x3f800000u) - 1.0f;
    bool bit = (f < probs[(p * 64 + i) * 64 + j]);
    u64 rm = __ballot(bit);
    if (j == 0) grow[ps * 64 + i] = rm;
    if (bit) colmask |= (1ull << i);
  }
  gcol[ps * 64 + j] = colmask;
}

__device__ __forceinline__ float rdlane(float x, int l) {
  return __uint_as_float(__builtin_amdgcn_readlane(__float_as_uint(x), (u32)l));
}

// Merged hybrid f32 LDL Cholesky (one launch per pass):
//  - All rows keep cols 0..39 in v[40] registers (proven 44-VGPR light path;
//    bit-identical math for m<=40 tasks).
//  - Heavy tasks (m>40, ~2%): trailing cols 40..m-1 live in LDS; phase-1
//    updates them with rdlane(v[k],b) (uniform b -> SGPR lane select, own-row
//    RMW, no barriers); short phase-2 LDS LDL for k>=40.
//  r12's v[64] heavy path cost VGPR 80 (-25us); r13's split serialized heavy
//  (-32us); r14's full-LDS heavy was latency-bound in the tail (-109us).
template<bool TRANSPOSE>
__global__ __launch_bounds__(64) void k_chol(const float* Rf, const double* ctab,
                                             const u64* masks, double* nodescore) {
  __shared__ float T[2080];
  __shared__ int idx[64];
  int task = blockIdx.x;
  int j = task & 63;
  int lane = threadIdx.x;
  u64 mask;
  if (TRANSPOSE) {
    int p = task >> 6;
    u64 rm = masks[p * 64 + lane];       // row mask of row `lane`
    mask = __ballot((rm >> j) & 1ull);   // column j mask
  } else {
    mask = masks[task];
  }
  int P = (int)__popcll(mask);
  int m = P + 1;
  u64 below = mask & ((1ull << lane) - 1ull);
  if ((mask >> lane) & 1ull) idx[(int)__popcll(below)] = lane;
  if (lane == 0) idx[P] = j;
  __syncthreads();
  int trLane = (lane * (lane + 1)) >> 1;
  if (lane < m) {
    int cidx = idx[lane];
    int tr = 0;
    for (int r = 0; r < m; r++) {
      if (lane <= r) T[tr + lane] = Rf[idx[r] * 64 + cidx];
      tr += r + 1;
    }
  }
  __syncthreads();
  float mypiv = 1.0f, lastd = 1.0f;
  // phase 1: pivots 0..39; register cols + (heavy-only) LDS trailing cols
  {
    float v[40];
#pragma unroll
    for (int c = 0; c < 40; c++)
      v[c] = T[trLane + c];              // in-bounds garbage for c>lane
#pragma unroll
    for (int k = 0; k < 40; k++) {
      if (k < m) {                       // uniform guard (keeps full unroll)
        float dk = rdlane(v[k], k);
        if (lane == k) mypiv = dk;
        lastd = dk;
        float ns = -v[k] * __builtin_amdgcn_rcpf(dk);
#pragma unroll
        for (int b = k + 1; b < 40; b++)
          v[b] += ns * rdlane(v[k], b);  // garbage slots harmless
        for (int b = 40; b < m; b++) {   // heavy only (empty when m<=40)
          float abk = rdlane(v[k], b);   // row b's col k (register, SGPR lane)
          if (lane >= b) T[trLane + b] += ns * abk;  // own-row RMW, no barrier
        }
      }
    }
  }
  // phase 2: pivots 40..m-1 in LDS (heavy tasks only, block-uniform)
  if (m > 40) {
    __syncthreads();
    for (int k = 40; k < m; k++) {
      float dk = T[((k * (k + 1)) >> 1) + k];        // broadcast
      if (lane == k) mypiv = dk;
      lastd = dk;
      float sk = T[trLane + k] * __builtin_amdgcn_rcpf(dk);
      for (int b = k + 1; b < m; b++) {
        float abk = T[((b * (b + 1)) >> 1) + k];     // broadcast
        if (lane >= b) T[trLane + b] -= sk * abk;    // predicate: tri overlap!
      }
      __syncthreads();
    }
  }
  double vv = (lane < m) ? log((double)mypiv) : 0.0;
  for (int off = 32; off > 0; off >>= 1) vv += __shfl_down(vv, off, 64);
  if (lane == 0) {
    double logB = vv;
    double logA = logB - log((double)lastd);
    double l = (double)P;
    nodescore[task] = ctab[P]
                    + 0.5 * (2050.0 + l) * logA
                    - 0.5 * (2051.0 + l) * logB;
  }
}

__global__ void k_logpw(const double* ns, double* w) {
  int p = blockIdx.x, t = threadIdx.x;
  __shared__ double part[64];
  int s = t & 15, c = t >> 4;            // 4 chunks x 16 samples
  double acc = 0.0;
  for (int j = c * 16; j < (c + 1) * 16; j++)
    acc += ns[(p * 16 + s) * 64 + j];
  part[t] = acc;
  __syncthreads();
  if (t < 16) part[t] = part[t] + part[t + 16] + part[t + 32] + part[t + 48];
  __syncthreads();
  if (t == 0) {
    double m = part[0];
    for (int s2 = 1; s2 < 16; s2++) m = fmax(m, part[s2]);
    double e[16], sum = 0.0;
    for (int s2 = 0; s2 < 16; s2++) { e[s2] = exp(part[s2] - m); sum += e[s2]; }
    for (int s2 = 0; s2 < 16; s2++) w[p * 16 + s2] = e[s2] / sum;
  }
}

// fused A-construction + grad dot + kmat.
// blocks 0..2047: grad_u; 2048..4095: grad_v; 4096..5119: Kmat (z0-only).
__global__ void k_grad(double* ws, const float* z) {
  const float* probs = (const float*)(ws + PROBS_OFF);
  const double* w = ws + W_OFF;
  const u64* grow = (const u64*)(ws + GROW_OFF);
  const u64* gcol = (const u64*)(ws + GCOL_OFF);
  float* gf = (float*)(ws + GF_OFF);
  const float LOGIT = -2.6903717578966254f;  // log(4/63)-log1p(-4/63)
  int bb = blockIdx.x;
  int k = threadIdx.x;
  __shared__ float acc[64];
  if (bb < 2048) {
    int p = bb >> 6, i = bb & 63;
    float gb = 0.f, wsum = 0.f;
    for (int s = 0; s < 16; s++) {
      float wv = (float)w[p * 16 + s];
      wsum += wv;
      gb += wv * (float)((grow[(p * 16 + s) * 64 + i] >> k) & 1ull);
    }
    float pr = probs[(p * 64 + i) * 64 + k];   // coalesced
    float od = (i == k) ? 0.f : 1.f;
    acc[k] = (0.2f * (gb - pr * wsum) + 0.2f * pr * (1.f - pr) * LOGIT) * od;
    __syncthreads();
    float s = 0.f;
    for (int j = 0; j < 64; j++)
      s += acc[j] * z[((p * 64 + j) * 64 + k) * 2 + 1];
    s -= 64.f * z[((p * 64 + i) * 64 + k) * 2 + 0];
    gf[p * 8192 + (i * 64 + k) * 2 + 0] = s;
  } else if (bb < 4096) {
    int b = bb - 2048;
    int p = b >> 6, j = b & 63;
    float gb = 0.f, wsum = 0.f;
    for (int s = 0; s < 16; s++) {
      float wv = (float)w[p * 16 + s];
      wsum += wv;
      gb += wv * (float)((gcol[(p * 16 + s) * 64 + j] >> k) & 1ull);
    }
    float pr = probs[(p * 64 + k) * 64 + j];   // one 64-lane gather
    float od = (k == j) ? 0.f : 1.f;
    acc[k] = (0.2f * (gb - pr * wsum) + 0.2f * pr * (1.f - pr) * LOGIT) * od;
    __syncthreads();
    float s = 0.f;
    for (int i = 0; i < 64; i++)
      s += acc[i] * z[((p * 64 + i) * 64 + k) * 2 + 0];
    s -= 64.f * z[((p * 64 + j) * 64 + k) * 2 + 1];
    gf[p * 8192 + (j * 64 + k) * 2 + 1] = s;
  } else {
    float* Km = (float*)(ws + KM_OFF);
    int b = bb - 4096;
    int a = b >> 5, b2 = b & 31;
    float accf = 0.f;
    for (int d0 = k; d0 < 8192; d0 += 64) {
      float diff = z[a * 8192 + d0] - z[b2 * 8192 + d0];
      accf += diff * diff;
    }
    for (int off = 32; off > 0; off >>= 1) accf += __shfl_down(accf, off, 64);
    if (k == 0) Km[a * 32 + b2] = expf(-accf / 5.0f);
  }
}

__global__ void k_znew(const float* z, double* ws, float* out) {
  const float* Km = (const float*)(ws + KM_OFF);
  const float* gf = (const float*)(ws + GF_OFF);
  float* zn = (float*)(ws + ZN_OFF);
  int gid = blockIdx.x * 64 + threadIdx.x;
  int p = gid >> 13, t = gid & 8191;
  float zp = z[p * 8192 + t];
  float accg = 0.f, accz = 0.f, ks = 0.f;
  for (int b = 0; b < 32; b++) {
    float kv = Km[p * 32 + b];
    accg += kv * gf[b * 8192 + t];
    accz += kv * z[b * 8192 + t];
    ks += kv;
  }
  float rep = -0.4f * (accz - zp * ks);
  float v = zp + 0.005f * ((accg + rep) / 32.f);
  zn[p * 8192 + t] = v;
  out[O_ZN + p * 8192 + t] = v;
}

__global__ __launch_bounds__(64) void k_s2col(double* ws, float* out) {
  const float* zn = (const float*)(ws + ZN_OFF);
  u64* grow2 = (u64*)(ws + NS_OFF);
  int b = blockIdx.x; int p = b >> 6, i = b & 63;
  int j = threadIdx.x;
  __shared__ float V[64 * 65];
  __shared__ float us[64];
  int k = j;
  us[k] = zn[p * 8192 + (i * 64 + k) * 2 + 0];
  for (int jj = 0; jj < 64; jj++)
    V[jj * 65 + k] = zn[p * 8192 + (jj * 64 + k) * 2 + 1];
  __syncthreads();
  float s = 0.f;
  for (int kk = 0; kk < 64; kk++)
    s += us[kk] * V[j * 65 + kk];
  bool bit = (i != j) && (s > 0.0f);
  out[O_GH + (p * 64 + i) * 64 + j] = bit ? 1.0f : 0.0f;
  u64 m = __ballot(bit);
  if (j == 0) grow2[p * 64 + i] = m;    // row masks; k_chol<true> transposes
}

// encoder/decoder MLP; also writes log_p (fused reduction)
__global__ void k_mlp(double* ws, float* out, const double* ns2,
    const float* ew0, const float* eb0, const float* ew1, const float* eb1,
    const float* ew2, const float* eb2,
    const float* mw0, const float* mb0, const float* mw1, const float* mb1,
    const float* lw0, const float* lb0, const float* lw1, const float* lb1,
    const float* dw0, const float* db0, const float* dw1, const float* db1,
    const float* dw2, const float* db2) {
  int p = blockIdx.x, t = threadIdx.x;
  const u64* grow2 = (const u64*)(ws + NS_OFF);
  const u32* keys = (const u32*)(ws + KEYS_OFF);
  __shared__ float part[64][20];
  __shared__ float h0[20], h1[64], h2[64], hm[64], hl[64];
  __shared__ float qmu[64], qlv[64], qz[64], h3[10], h4[128];
  __shared__ u64 gc[64];
  {
    double vv = ns2[p * 64 + t];
    for (int off = 32; off > 0; off >>= 1) vv += __shfl_down(vv, off, 64);
    if (t == 0) out[O_LOGP + p] = (float)vv;
  }
  // column mask: bit i of gc[t] = (rowmask_i >> t) & 1
  {
    u64 cmask = 0;
    for (int i = 0; i < 64; i++)
      cmask |= ((grow2[p * 64 + i] >> t) & 1ull) << i;
    gc[t] = cmask;
  }
  __syncthreads();
  {
    float acc[20];
#pragma unroll
    for (int o = 0; o < 20; o++) acc[o] = 0.f;
    u64 m = gc[t];
    for (int i = 0; i < 64; i++) {
      float msk = (float)((m >> i) & 1ull);
      const float* wr = ew0 + (i * 64 + t) * 20;
#pragma unroll
      for (int o = 0; o < 20; o++) acc[o] += msk * wr[o];
    }
    for (int o = 0; o < 20; o++) part[t][o] = acc[o];
  }
  __syncthreads();
  if (t < 20) {
    float s = eb0[t];
    for (int q = 0; q < 64; q++) s += part[q][t];
    h0[t] = fmaxf(s, 0.f);
  }
  __syncthreads();
  {
    float s = eb1[t];
    for (int q = 0; q < 20; q++) s += h0[q] * ew1[q * 64 + t];
    h1[t] = fmaxf(s, 0.f);
  }
  __syncthreads();
  {
    float s = eb2[t];
    for (int q = 0; q < 64; q++) s += h1[q] * ew2[q * 64 + t];
    h2[t] = fmaxf(s, 0.f);
  }
  __syncthreads();
  {
    float s = mb0[t];
    for (int q = 0; q < 64; q++) s += h2[q] * mw0[q * 64 + t];
    hm[t] = fmaxf(s, 0.f);
    float s2 = lb0[t];
    for (int q = 0; q < 64; q++) s2 += h2[q] * lw0[q * 64 + t];
    hl[t] = fmaxf(s2, 0.f);
  }
  __syncthreads();
  {
    float s = mb1[t];
    for (int q = 0; q < 64; q++) s += hm[q] * mw1[q * 64 + t];
    qmu[t] = s;
    float s2 = lb1[t];
    for (int q = 0; q < 64; q++) s2 += hl[q] * lw1[q * 64 + t];
    qlv[t] = s2;
  }
  {
    u32 o0, o1;
    tf2x32(keys[2], keys[3], 0u, (u32)(p * 64 + t), o0, o1);
    u32 bits = o0 ^ o1;
    float f = __uint_as_float((bits >> 9) | 0x3f800000u) - 1.0f;
    float LOF = __uint_as_float(0xBF7FFFFFu);
    float uu = fmaxf(LOF, f * 2.0f + LOF);
    float eps = (float)(1.4142135623730951 * d_erfinv((double)uu));
    float qzv = qmu[t] + eps * expf(0.5f * qlv[t]);
    qz[t] = qzv;
    out[O_QZ  + p * 64 + t] = qzv;
    out[O_QMU + p * 64 + t] = qmu[t];
    out[O_QLV + p * 64 + t] = qlv[t];
  }
  __syncthreads();
  if (t < 10) {
    float s = db0[t];
    for (int q = 0; q < 64; q++) s += qz[q] * dw0[q * 10 + t];
    h3[t] = fmaxf(s, 0.f);
  }
  __syncthreads();
  for (int o = t; o < 128; o += 64) {
    float s = db1[o];
    for (int q = 0; q < 10; q++) s += h3[q] * dw1[q * 128 + o];
    h4[o] = fmaxf(s, 0.f);
  }
  __syncthreads();
  for (int o = t; o < 128; o += 64) {
    float s = db2[o];
    for (int q = 0; q < 128; q++) s += h4[q] * dw2[q * 128 + o];
    out[O_REC + p * 128 + o] = s;
  }
}

extern "C" void kernel_launch(void* const* d_in, const int* in_sizes, int n_in,
                              void* d_out, int out_size, void* d_ws, size_t ws_size,
                              hipStream_t stream) {
  (void)in_sizes; (void)n_in; (void)out_size; (void)ws_size;
  const float* z_gt = (const float*)d_in[0];
  const float* z0   = (const float*)d_in[1];
  const float* ew0 = (const float*)d_in[2];  const float* eb0 = (const float*)d_in[3];
  const float* ew1 = (const float*)d_in[4];  const float* eb1 = (const float*)d_in[5];
  const float* ew2 = (const float*)d_in[6];  const float* eb2 = (const float*)d_in[7];
  const float* mw0 = (const float*)d_in[8];  const float* mb0 = (const float*)d_in[9];
  const float* mw1 = (const float*)d_in[10]; const float* mb1 = (const float*)d_in[11];
  const float* lw0 = (const float*)d_in[12]; const float* lb0 = (const float*)d_in[13];
  const float* lw1 = (const float*)d_in[14]; const float* lb1 = (const float*)d_in[15];
  const float* dw0 = (const float*)d_in[16]; const float* db0 = (const float*)d_in[17];
  const float* dw1 = (const float*)d_in[18]; const float* db1 = (const float*)d_in[19];
  const float* dw2 = (const float*)d_in[20]; const float* db2 = (const float*)d_in[21];
  const int* seed = (const int*)d_in[22];
  double* ws = (double*)d_ws;
  float* out = (float*)d_out;
  const float* Rf = (const float*)(ws + R_OFF);

  k_R<<<64, 512, 0, stream>>>(z_gt, ws, seed);
  k_probs<<<C_P * C_D, 64, 0, stream>>>(z0, ws);
  k_sample<<<C_P * C_S, 64, 0, stream>>>(ws);
  k_chol<false><<<C_P * C_S * C_D, 64, 0, stream>>>(Rf, ws + CTAB_OFF,
      (const u64*)(ws + GCOL_OFF), ws + NS_OFF);
  k_logpw<<<C_P, 64, 0, stream>>>(ws + NS_OFF, ws + W_OFF);
  k_grad<<<2 * C_P * C_D + C_P * C_P, 64, 0, stream>>>(ws, z0);
  k_znew<<<(C_P * 8192) / 64, 64, 0, stream>>>(z0, ws, out);
  k_s2col<<<C_P * C_D, 64, 0, stream>>>(ws, out);
  k_chol<true><<<C_P * C_D, 64, 0, stream>>>(Rf, ws + CTAB_OFF,
      (const u64*)(ws + NS_OFF), ws + NS2_OFF);
  k_mlp<<<C_P, 64, 0, stream>>>(ws, out, ws + NS2_OFF,
      ew0, eb0, ew1, eb1, ew2, eb2,
      mw0, mb0, mw1, mb1, lw0, lb0, lw1, lb1,
      dw0, db0, dw1, db1, dw2, db2);
}

// Round 16
// 380.559 us; speedup vs baseline: 1.3539x; 1.0552x over previous
//
#include <hip/hip_runtime.h>
#include <stdint.h>
#include <math.h>

typedef unsigned long long u64;
typedef unsigned int u32;
typedef unsigned short u16;

// ---- problem constants ----
#define C_P 32
#define C_S 16
#define C_D 64
#define C_N 2048

// ---- ws layout (offsets in doubles) ----
#define R_OFF      0        // float[4096]
#define CTAB_OFF   4160     // double[64]
#define KEYS_OFF   4224     // u32[4]
#define PROBS_OFF  4232     // float[131072]
#define GROW_OFF   135304   // u64[32768] row masks
#define GCOL_OFF   168072   // u64[32768] col masks
#define NS_OFF     200840   // double[32768]; later grow2 u64[2048]
#define W_OFF      233608   // double[512]
#define GF_OFF     234120   // float[262144]
#define KM_OFF     365192   // float[1024]
#define ZN_OFF     365704   // float[262144]
#define NS2_OFF    496776   // double[2048]

// ---- out layout (FLOAT32 elements) ----
#define O_REC   0
#define O_LOGP  4096
#define O_QZ    4128
#define O_QMU   6176
#define O_QLV   8224
#define O_GH    10272
#define O_ZN    141344
#define O_TOTAL 403488

__device__ __forceinline__ void tf2x32(u32 k0, u32 k1, u32 x0, u32 x1,
                                       u32& o0, u32& o1) {
  u32 ks2 = k0 ^ k1 ^ 0x1BD11BDAu;
  x0 += k0; x1 += k1;
#define TFR(r) { x0 += x1; x1 = (x1 << r) | (x1 >> (32 - r)); x1 ^= x0; }
  TFR(13) TFR(15) TFR(26) TFR(6)   x0 += k1;  x1 += ks2 + 1u;
  TFR(17) TFR(29) TFR(16) TFR(24)  x0 += ks2; x1 += k0 + 2u;
  TFR(13) TFR(15) TFR(26) TFR(6)   x0 += k0;  x1 += k1 + 3u;
  TFR(17) TFR(29) TFR(16) TFR(24)  x0 += k1;  x1 += ks2 + 4u;
  TFR(13) TFR(15) TFR(26) TFR(6)   x0 += ks2; x1 += k0 + 5u;
#undef TFR
  o0 = x0; o1 = x1;
}

__device__ __forceinline__ double d_erfinv(double x) {
  double w = -log1p(-x * x);
  double p;
  if (w < 5.0) {
    w -= 2.5;
    p = 2.81022636e-08;
    p = 3.43273939e-07  + p * w;
    p = -3.5233877e-06  + p * w;
    p = -4.39150654e-06 + p * w;
    p = 0.00021858087   + p * w;
    p = -0.00125372503  + p * w;
    p = -0.00417768164  + p * w;
    p = 0.246640727     + p * w;
    p = 1.50140941      + p * w;
  } else {
    w = sqrt(w) - 3.0;
    p = -0.000200214257;
    p = 0.000100950558  + p * w;
    p = 0.00134934322   + p * w;
    p = -0.00367342844  + p * w;
    p = 0.00573950773   + p * w;
    p = -0.0076224613   + p * w;
    p = 0.00943887047   + p * w;
    p = 1.00167406      + p * w;
    p = 2.83297682      + p * w;
  }
  return p * x;
}

// R (with fused setup on block 0): one pass Sx/Sxx, combine analytically.
__global__ void k_R(const float* x, double* ws, const int* seedp) {
  __shared__ double pS[8][64], pX[8][64];
  __shared__ double xbar[64];
  int j = blockIdx.x, t = threadIdx.x;   // 512 threads
  int i = t & 63, c = t >> 6;
  if (j == 0) {                          // fused k_setup
    if (t < 64) {
      double l = (double)t;
      ws[CTAB_OFF + t] = -0.5 * log(2049.0)
                       + lgamma(0.5 * (2051.0 + l))
                       - lgamma(0.5 * (3.0 + l))
                       - 1024.0 * log(3.14159265358979323846)
                       + 0.5 * (2.0 * l + 3.0) * log(0.5);
    }
    if (t == 0) {
      u32 kk0 = 0u, kk1 = (u32)seedp[0];
      u32 a0, a1, s0, s1, r0, r1, d0, d1;
      tf2x32(kk0, kk1, 0u, 0u, a0, a1);
      tf2x32(kk0, kk1, 0u, 1u, s0, s1);   // sk (bernoulli)
      tf2x32(a0, a1, 0u, 0u, d0, d1); (void)d0; (void)d1;
      tf2x32(a0, a1, 0u, 1u, r0, r1);     // rk (normal eps)
      u32* keys = (u32*)(ws + KEYS_OFF);
      keys[0] = s0; keys[1] = s1; keys[2] = r0; keys[3] = r1;
    }
  }
  double sx = 0.0, sxx = 0.0;
  for (int n = c * 256; n < (c + 1) * 256; n++) {
    double xi = (double)x[n * 64 + i];
    double xj = (double)x[n * 64 + j];
    sx += xi; sxx += xi * xj;
  }
  pS[c][i] = sx; pX[c][i] = sxx;
  __syncthreads();
  if (t < 64) {
    double S = 0.0, X = 0.0;
    for (int cc = 0; cc < 8; cc++) { S += pS[cc][i]; X += pX[cc][i]; }
    xbar[i] = S / 2048.0;
    pX[0][i] = X;
  }
  __syncthreads();
  if (t < 64) {
    double xbi = xbar[i], xbj = xbar[j];
    double s = pX[0][i] - 2048.0 * xbi * xbj + (2048.0 / 2049.0) * xbi * xbj;
    if (i == j) s += 0.5;
    ((float*)(ws + R_OFF))[i * 64 + j] = (float)s;
  }
}

// probs[p,i,j] = sigmoid(alpha * u_i . v_j) * (i!=j), stored f32
__global__ __launch_bounds__(64) void k_probs(const float* z, double* ws) {
  float* probs = (float*)(ws + PROBS_OFF);
  int b = blockIdx.x; int p = b >> 6, i = b & 63;
  int j = threadIdx.x;
  __shared__ float V[64 * 65];
  __shared__ float us[64];
  int k = j;
  us[k] = z[((p * 64 + i) * 64 + k) * 2 + 0];
  for (int jj = 0; jj < 64; jj++)
    V[jj * 65 + k] = z[((p * 64 + jj) * 64 + k) * 2 + 1];
  __syncthreads();
  float s = 0.f;
  for (int kk = 0; kk < 64; kk++)
    s += us[kk] * V[j * 65 + kk];
  float pr = (i == j) ? 0.f : 1.f / (1.f + expf(-0.2f * s));
  probs[(p * 64 + i) * 64 + j] = pr;
}

__global__ void k_sample(double* ws) {
  const float* probs = (const float*)(ws + PROBS_OFF);
  const u32* keys = (const u32*)(ws + KEYS_OFF);
  u64* grow = (u64*)(ws + GROW_OFF);
  u64* gcol = (u64*)(ws + GCOL_OFF);
  int ps = blockIdx.x;
  int p = ps >> 4;
  int j = threadIdx.x;
  u32 k0 = keys[0], k1 = keys[1];
  u64 colmask = 0;
  for (int i = 0; i < 64; i++) {
    u32 lin = (u32)(ps * 4096 + i * 64 + j);
    u32 o0, o1; tf2x32(k0, k1, 0u, lin, o0, o1);
    u32 bits = o0 ^ o1;
    float f = __uint_as_float((bits >> 9) | 0x3f800000u) - 1.0f;
    bool bit = (f < probs[(p * 64 + i) * 64 + j]);
    u64 rm = __ballot(bit);
    if (j == 0) grow[ps * 64 + i] = rm;
    if (bit) colmask |= (1ull << i);
  }
  gcol[ps * 64 + j] = colmask;
}

__device__ __forceinline__ float rdlane(float x, int l) {
  return __uint_as_float(__builtin_amdgcn_readlane(__float_as_uint(x), (u32)l));
}

// Merged hybrid f32 LDL Cholesky, one launch per pass.
// Light path (m<=40, ~98%): pure r13 register k-loop — NO embedded dynamic
// loops (r15's per-k trailing loop cost ~16us of issue/I-cache overhead on
// light tasks). Heavy tasks (m>40): trailing cols updated AFTER the k-loop
// in one pass (valid because column-k values are final at step k:
// T[lane][b] -= sum_k v[k]_lane * v[k]_b / d_k), then short phase-2 LDS LDL.
template<bool TRANSPOSE>
__global__ __launch_bounds__(64) void k_chol(const float* Rf, const double* ctab,
                                             const u64* masks, double* nodescore) {
  __shared__ float T[2080];
  __shared__ int idx[64];
  int task = blockIdx.x;
  int j = task & 63;
  int lane = threadIdx.x;
  u64 mask;
  if (TRANSPOSE) {
    int p = task >> 6;
    u64 rm = masks[p * 64 + lane];       // row mask of row `lane`
    mask = __ballot((rm >> j) & 1ull);   // column j mask
  } else {
    mask = masks[task];
  }
  int P = (int)__popcll(mask);
  int m = P + 1;
  u64 below = mask & ((1ull << lane) - 1ull);
  if ((mask >> lane) & 1ull) idx[(int)__popcll(below)] = lane;
  if (lane == 0) idx[P] = j;
  __syncthreads();
  int trLane = (lane * (lane + 1)) >> 1;
  if (lane < m) {
    int cidx = idx[lane];
    int tr = 0;
    for (int r = 0; r < m; r++) {
      if (lane <= r) T[tr + lane] = Rf[idx[r] * 64 + cidx];
      tr += r + 1;
    }
  }
  __syncthreads();
  float mypiv = 1.0f, lastd = 1.0f;
  float v[40];
#pragma unroll
  for (int c = 0; c < 40; c++)
    v[c] = T[trLane + c];                // in-bounds garbage for c>lane
#pragma unroll
  for (int k = 0; k < 40; k++) {
    if (k < m) {                         // uniform guard (keeps full unroll)
      float dk = rdlane(v[k], k);
      if (lane == k) mypiv = dk;
      lastd = dk;
      float ns = -v[k] * __builtin_amdgcn_rcpf(dk);
#pragma unroll
      for (int b = k + 1; b < 40; b++)
        v[b] += ns * rdlane(v[k], b);    // garbage slots harmless
    }
  }
  if (m > 40) {                          // heavy tasks only (block-uniform)
    // one-shot trailing update: col-k values are final after the k-loop
    for (int b = 40; b < m; b++) {
      float acc = 0.f;
#pragma unroll
      for (int k = 0; k < 40; k++) {
        float dk = rdlane(v[k], k);                  // final pivot k
        float abk = rdlane(v[k], b);                 // final A[b][k]
        acc += v[k] * abk * __builtin_amdgcn_rcpf(dk);
      }
      if (lane >= b) T[trLane + b] -= acc;           // own-row, no conflict
    }
    __syncthreads();
    // phase 2: pivots 40..m-1 in LDS
    for (int k = 40; k < m; k++) {
      float dk = T[((k * (k + 1)) >> 1) + k];        // broadcast
      if (lane == k) mypiv = dk;
      lastd = dk;
      float sk = T[trLane + k] * __builtin_amdgcn_rcpf(dk);
      for (int b = k + 1; b < m; b++) {
        float abk = T[((b * (b + 1)) >> 1) + k];     // broadcast
        if (lane >= b) T[trLane + b] -= sk * abk;
      }
      __syncthreads();
    }
  }
  double vv = (lane < m) ? log((double)mypiv) : 0.0;
  for (int off = 32; off > 0; off >>= 1) vv += __shfl_down(vv, off, 64);
  if (lane == 0) {
    double logB = vv;
    double logA = logB - log((double)lastd);
    double l = (double)P;
    nodescore[task] = ctab[P]
                    + 0.5 * (2050.0 + l) * logA
                    - 0.5 * (2051.0 + l) * logB;
  }
}

__global__ void k_logpw(const double* ns, double* w) {
  int p = blockIdx.x, t = threadIdx.x;
  __shared__ double part[64];
  int s = t & 15, c = t >> 4;            // 4 chunks x 16 samples
  double acc = 0.0;
  for (int j = c * 16; j < (c + 1) * 16; j++)
    acc += ns[(p * 16 + s) * 64 + j];
  part[t] = acc;
  __syncthreads();
  if (t < 16) part[t] = part[t] + part[t + 16] + part[t + 32] + part[t + 48];
  __syncthreads();
  if (t == 0) {
    double m = part[0];
    for (int s2 = 1; s2 < 16; s2++) m = fmax(m, part[s2]);
    double e[16], sum = 0.0;
    for (int s2 = 0; s2 < 16; s2++) { e[s2] = exp(part[s2] - m); sum += e[s2]; }
    for (int s2 = 0; s2 < 16; s2++) w[p * 16 + s2] = e[s2] / sum;
  }
}

// fused A-construction + grad dot + kmat.
// blocks 0..2047: grad_u; 2048..4095: grad_v; 4096..5119: Kmat (z0-only).
__global__ void k_grad(double* ws, const float* z) {
  const float* probs = (const float*)(ws + PROBS_OFF);
  const double* w = ws + W_OFF;
  const u64* grow = (const u64*)(ws + GROW_OFF);
  const u64* gcol = (const u64*)(ws + GCOL_OFF);
  float* gf = (float*)(ws + GF_OFF);
  const float LOGIT = -2.6903717578966254f;  // log(4/63)-log1p(-4/63)
  int bb = blockIdx.x;
  int k = threadIdx.x;
  __shared__ float acc[64];
  if (bb < 2048) {
    int p = bb >> 6, i = bb & 63;
    float gb = 0.f, wsum = 0.f;
    for (int s = 0; s < 16; s++) {
      float wv = (float)w[p * 16 + s];
      wsum += wv;
      gb += wv * (float)((grow[(p * 16 + s) * 64 + i] >> k) & 1ull);
    }
    float pr = probs[(p * 64 + i) * 64 + k];   // coalesced
    float od = (i == k) ? 0.f : 1.f;
    acc[k] = (0.2f * (gb - pr * wsum) + 0.2f * pr * (1.f - pr) * LOGIT) * od;
    __syncthreads();
    float s = 0.f;
    for (int j = 0; j < 64; j++)
      s += acc[j] * z[((p * 64 + j) * 64 + k) * 2 + 1];
    s -= 64.f * z[((p * 64 + i) * 64 + k) * 2 + 0];
    gf[p * 8192 + (i * 64 + k) * 2 + 0] = s;
  } else if (bb < 4096) {
    int b = bb - 2048;
    int p = b >> 6, j = b & 63;
    float gb = 0.f, wsum = 0.f;
    for (int s = 0; s < 16; s++) {
      float wv = (float)w[p * 16 + s];
      wsum += wv;
      gb += wv * (float)((gcol[(p * 16 + s) * 64 + j] >> k) & 1ull);
    }
    float pr = probs[(p * 64 + k) * 64 + j];   // one 64-lane gather
    float od = (k == j) ? 0.f : 1.f;
    acc[k] = (0.2f * (gb - pr * wsum) + 0.2f * pr * (1.f - pr) * LOGIT) * od;
    __syncthreads();
    float s = 0.f;
    for (int i = 0; i < 64; i++)
      s += acc[i] * z[((p * 64 + i) * 64 + k) * 2 + 0];
    s -= 64.f * z[((p * 64 + j) * 64 + k) * 2 + 1];
    gf[p * 8192 + (j * 64 + k) * 2 + 1] = s;
  } else {
    float* Km = (float*)(ws + KM_OFF);
    int b = bb - 4096;
    int a = b >> 5, b2 = b & 31;
    float accf = 0.f;
    for (int d0 = k; d0 < 8192; d0 += 64) {
      float diff = z[a * 8192 + d0] - z[b2 * 8192 + d0];
      accf += diff * diff;
    }
    for (int off = 32; off > 0; off >>= 1) accf += __shfl_down(accf, off, 64);
    if (k == 0) Km[a * 32 + b2] = expf(-accf / 5.0f);
  }
}

__global__ void k_znew(const float* z, double* ws, float* out) {
  const float* Km = (const float*)(ws + KM_OFF);
  const float* gf = (const float*)(ws + GF_OFF);
  float* zn = (float*)(ws + ZN_OFF);
  int gid = blockIdx.x * 64 + threadIdx.x;
  int p = gid >> 13, t = gid & 8191;
  float zp = z[p * 8192 + t];
  float accg = 0.f, accz = 0.f, ks = 0.f;
  for (int b = 0; b < 32; b++) {
    float kv = Km[p * 32 + b];
    accg += kv * gf[b * 8192 + t];
    accz += kv * z[b * 8192 + t];
    ks += kv;
  }
  float rep = -0.4f * (accz - zp * ks);
  float v = zp + 0.005f * ((accg + rep) / 32.f);
  zn[p * 8192 + t] = v;
  out[O_ZN + p * 8192 + t] = v;
}

__global__ __launch_bounds__(64) void k_s2col(double* ws, float* out) {
  const float* zn = (const float*)(ws + ZN_OFF);
  u64* grow2 = (u64*)(ws + NS_OFF);
  int b = blockIdx.x; int p = b >> 6, i = b & 63;
  int j = threadIdx.x;
  __shared__ float V[64 * 65];
  __shared__ float us[64];
  int k = j;
  us[k] = zn[p * 8192 + (i * 64 + k) * 2 + 0];
  for (int jj = 0; jj < 64; jj++)
    V[jj * 65 + k] = zn[p * 8192 + (jj * 64 + k) * 2 + 1];
  __syncthreads();
  float s = 0.f;
  for (int kk = 0; kk < 64; kk++)
    s += us[kk] * V[j * 65 + kk];
  bool bit = (i != j) && (s > 0.0f);
  out[O_GH + (p * 64 + i) * 64 + j] = bit ? 1.0f : 0.0f;
  u64 m = __ballot(bit);
  if (j == 0) grow2[p * 64 + i] = m;    // row masks; k_chol<true> transposes
}

// encoder/decoder MLP; also writes log_p (fused reduction)
__global__ void k_mlp(double* ws, float* out, const double* ns2,
    const float* ew0, const float* eb0, const float* ew1, const float* eb1,
    const float* ew2, const float* eb2,
    const float* mw0, const float* mb0, const float* mw1, const float* mb1,
    const float* lw0, const float* lb0, const float* lw1, const float* lb1,
    const float* dw0, const float* db0, const float* dw1, const float* db1,
    const float* dw2, const float* db2) {
  int p = blockIdx.x, t = threadIdx.x;
  const u64* grow2 = (const u64*)(ws + NS_OFF);
  const u32* keys = (const u32*)(ws + KEYS_OFF);
  __shared__ float part[64][20];
  __shared__ float h0[20], h1[64], h2[64], hm[64], hl[64];
  __shared__ float qmu[64], qlv[64], qz[64], h3[10], h4[128];
  __shared__ u64 gc[64];
  {
    double vv = ns2[p * 64 + t];
    for (int off = 32; off > 0; off >>= 1) vv += __shfl_down(vv, off, 64);
    if (t == 0) out[O_LOGP + p] = (float)vv;
  }
  // column mask: bit i of gc[t] = (rowmask_i >> t) & 1
  {
    u64 cmask = 0;
    for (int i = 0; i < 64; i++)
      cmask |= ((grow2[p * 64 + i] >> t) & 1ull) << i;
    gc[t] = cmask;
  }
  __syncthreads();
  {
    float acc[20];
#pragma unroll
    for (int o = 0; o < 20; o++) acc[o] = 0.f;
    u64 m = gc[t];
    for (int i = 0; i < 64; i++) {
      float msk = (float)((m >> i) & 1ull);
      const float* wr = ew0 + (i * 64 + t) * 20;
#pragma unroll
      for (int o = 0; o < 20; o++) acc[o] += msk * wr[o];
    }
    for (int o = 0; o < 20; o++) part[t][o] = acc[o];
  }
  __syncthreads();
  if (t < 20) {
    float s = eb0[t];
    for (int q = 0; q < 64; q++) s += part[q][t];
    h0[t] = fmaxf(s, 0.f);
  }
  __syncthreads();
  {
    float s = eb1[t];
    for (int q = 0; q < 20; q++) s += h0[q] * ew1[q * 64 + t];
    h1[t] = fmaxf(s, 0.f);
  }
  __syncthreads();
  {
    float s = eb2[t];
    for (int q = 0; q < 64; q++) s += h1[q] * ew2[q * 64 + t];
    h2[t] = fmaxf(s, 0.f);
  }
  __syncthreads();
  {
    float s = mb0[t];
    for (int q = 0; q < 64; q++) s += h2[q] * mw0[q * 64 + t];
    hm[t] = fmaxf(s, 0.f);
    float s2 = lb0[t];
    for (int q = 0; q < 64; q++) s2 += h2[q] * lw0[q * 64 + t];
    hl[t] = fmaxf(s2, 0.f);
  }
  __syncthreads();
  {
    float s = mb1[t];
    for (int q = 0; q < 64; q++) s += hm[q] * mw1[q * 64 + t];
    qmu[t] = s;
    float s2 = lb1[t];
    for (int q = 0; q < 64; q++) s2 += hl[q] * lw1[q * 64 + t];
    qlv[t] = s2;
  }
  {
    u32 o0, o1;
    tf2x32(keys[2], keys[3], 0u, (u32)(p * 64 + t), o0, o1);
    u32 bits = o0 ^ o1;
    float f = __uint_as_float((bits >> 9) | 0x3f800000u) - 1.0f;
    float LOF = __uint_as_float(0xBF7FFFFFu);
    float uu = fmaxf(LOF, f * 2.0f + LOF);
    float eps = (float)(1.4142135623730951 * d_erfinv((double)uu));
    float qzv = qmu[t] + eps * expf(0.5f * qlv[t]);
    qz[t] = qzv;
    out[O_QZ  + p * 64 + t] = qzv;
    out[O_QMU + p * 64 + t] = qmu[t];
    out[O_QLV + p * 64 + t] = qlv[t];
  }
  __syncthreads();
  if (t < 10) {
    float s = db0[t];
    for (int q = 0; q < 64; q++) s += qz[q] * dw0[q * 10 + t];
    h3[t] = fmaxf(s, 0.f);
  }
  __syncthreads();
  for (int o = t; o < 128; o += 64) {
    float s = db1[o];
    for (int q = 0; q < 10; q++) s += h3[q] * dw1[q * 128 + o];
    h4[o] = fmaxf(s, 0.f);
  }
  __syncthreads();
  for (int o = t; o < 128; o += 64) {
    float s = db2[o];
    for (int q = 0; q < 128; q++) s += h4[q] * dw2[q * 128 + o];
    out[O_REC + p * 128 + o] = s;
  }
}

extern "C" void kernel_launch(void* const* d_in, const int* in_sizes, int n_in,
                              void* d_out, int out_size, void* d_ws, size_t ws_size,
                              hipStream_t stream) {
  (void)in_sizes; (void)n_in; (void)out_size; (void)ws_size;
  const float* z_gt = (const float*)d_in[0];
  const float* z0   = (const float*)d_in[1];
  const float* ew0 = (const float*)d_in[2];  const float* eb0 = (const float*)d_in[3];
  const float* ew1 = (const float*)d_in[4];  const float* eb1 = (const float*)d_in[5];
  const float* ew2 = (const float*)d_in[6];  const float* eb2 = (const float*)d_in[7];
  const float* mw0 = (const float*)d_in[8];  const float* mb0 = (const float*)d_in[9];
  const float* mw1 = (const float*)d_in[10]; const float* mb1 = (const float*)d_in[11];
  const float* lw0 = (const float*)d_in[12]; const float* lb0 = (const float*)d_in[13];
  const float* lw1 = (const float*)d_in[14]; const float* lb1 = (const float*)d_in[15];
  const float* dw0 = (const float*)d_in[16]; const float* db0 = (const float*)d_in[17];
  const float* dw1 = (const float*)d_in[18]; const float* db1 = (const float*)d_in[19];
  const float* dw2 = (const float*)d_in[20]; const float* db2 = (const float*)d_in[21];
  const int* seed = (const int*)d_in[22];
  double* ws = (double*)d_ws;
  float* out = (float*)d_out;
  const float* Rf = (const float*)(ws + R_OFF);

  k_R<<<64, 512, 0, stream>>>(z_gt, ws, seed);
  k_probs<<<C_P * C_D, 64, 0, stream>>>(z0, ws);
  k_sample<<<C_P * C_S, 64, 0, stream>>>(ws);
  k_chol<false><<<C_P * C_S * C_D, 64, 0, stream>>>(Rf, ws + CTAB_OFF,
      (const u64*)(ws + GCOL_OFF), ws + NS_OFF);
  k_logpw<<<C_P, 64, 0, stream>>>(ws + NS_OFF, ws + W_OFF);
  k_grad<<<2 * C_P * C_D + C_P * C_P, 64, 0, stream>>>(ws, z0);
  k_znew<<<(C_P * 8192) / 64, 64, 0, stream>>>(z0, ws, out);
  k_s2col<<<C_P * C_D, 64, 0, stream>>>(ws, out);
  k_chol<true><<<C_P * C_D, 64, 0, stream>>>(Rf, ws + CTAB_OFF,
      (const u64*)(ws + NS_OFF), ws + NS2_OFF);
  k_mlp<<<C_P, 64, 0, stream>>>(ws, out, ws + NS2_OFF,
      ew0, eb0, ew1, eb1, ew2, eb2,
      mw0, mb0, mw1, mb1, lw0, lb0, lw1, lb1,
      dw0, db0, dw1, db1, dw2, db2);
}